// Round 1
// baseline (10792.743 us; speedup 1.0000x reference)
//
#include <hip/hip_runtime.h>
#include <hip/hip_bf16.h>
#include <math.h>

// Transformer fwd: L=6 H=16 DM=1024 DH=64 DFF=4096 V=32000 B=2 S=1024
// Round 0 baseline: fp32 tiled GEMMs (64x64 tile, 4x4 microtile), one-wave
// flash-ish attention, fused bias/relu epilogues, residual+LN fused kernel.

namespace {
constexpr int LAYERS = 6;
constexpr int NH     = 16;
constexpr int DMODEL = 1024;
constexpr int DHEAD  = 64;
constexpr int DFFN   = 4096;
constexpr int VOCAB  = 32000;
constexpr int BATCH  = 2;
constexpr int SEQ    = 1024;
constexpr int ROWS   = BATCH * SEQ;   // 2048
constexpr int QKVC   = 3 * DMODEL;    // 3072
}

// ---------------- embedding + positional encoding ----------------
__global__ __launch_bounds__(256)
void embed_kernel(const int* __restrict__ tokens,
                  const float* __restrict__ emb,
                  float* __restrict__ x)
{
    const int row = blockIdx.x;           // b*SEQ + s
    const int s = row & (SEQ - 1);
    const int tok = tokens[row];
    const int d0 = threadIdx.x * 4;
    const float c = -logf(10000.0f) / (float)DMODEL;
    float4 e = *reinterpret_cast<const float4*>(emb + (size_t)tok * DMODEL + d0);
    float v[4] = {e.x, e.y, e.z, e.w};
    float o[4];
#pragma unroll
    for (int u = 0; u < 4; ++u) {
        const int d = d0 + u;
        const float ang = (float)s * expf((float)(d & ~1) * c);
        const float pe = (d & 1) ? cosf(ang) : sinf(ang);
        o[u] = v[u] * 32.0f + pe;          // sqrt(1024) = 32
    }
    *reinterpret_cast<float4*>(x + (size_t)row * DMODEL + d0) =
        make_float4(o[0], o[1], o[2], o[3]);
}

// ---------------- generic fp32 GEMM: C = A @ B (+bias) (+relu) ----------------
// 64x64 tile, BK=16, 256 threads, 4x4 per-thread microtile.
// grid.z batching: B += z*bStride, C += z*cStride (for per-head QKV weights).
__global__ __launch_bounds__(256)
void gemm64_kernel(const float* __restrict__ A, int lda,
                   const float* __restrict__ Bm, int ldb, long long bStride,
                   float* __restrict__ C, int ldc, long long cStride,
                   const float* __restrict__ bias, int K, int doRelu)
{
    __shared__ float As[16][68];   // transposed: As[k][row], padded
    __shared__ float Bs[16][68];   // Bs[k][col], padded
    const int tx = threadIdx.x, ty = threadIdx.y;
    const int tid = ty * 16 + tx;
    const int rowBase = blockIdx.y * 64;
    const int colBase = blockIdx.x * 64;
    const float* Bz = Bm + (long long)blockIdx.z * bStride;
    float* Cz = C + (long long)blockIdx.z * cStride;

    const int ar = tid >> 2, ac = (tid & 3) * 4;   // A: 64 rows x 16 k
    const int br = tid >> 4, bc = (tid & 15) * 4;  // B: 16 k x 64 cols
    const float* aPtr = A + (size_t)(rowBase + ar) * lda + ac;
    const float* bPtr = Bz + (size_t)br * ldb + colBase + bc;

    float acc[4][4] = {};
    for (int k0 = 0; k0 < K; k0 += 16) {
        const float4 av = *reinterpret_cast<const float4*>(aPtr + k0);
        const float4 bv = *reinterpret_cast<const float4*>(bPtr + (size_t)k0 * ldb);
        As[ac + 0][ar] = av.x;
        As[ac + 1][ar] = av.y;
        As[ac + 2][ar] = av.z;
        As[ac + 3][ar] = av.w;
        *reinterpret_cast<float4*>(&Bs[br][bc]) = bv;
        __syncthreads();
#pragma unroll
        for (int kk = 0; kk < 16; ++kk) {
            float a[4], b[4];
#pragma unroll
            for (int i = 0; i < 4; ++i) a[i] = As[kk][ty * 4 + i];
            const float4 b4 = *reinterpret_cast<const float4*>(&Bs[kk][tx * 4]);
            b[0] = b4.x; b[1] = b4.y; b[2] = b4.z; b[3] = b4.w;
#pragma unroll
            for (int i = 0; i < 4; ++i)
#pragma unroll
                for (int j = 0; j < 4; ++j)
                    acc[i][j] = fmaf(a[i], b[j], acc[i][j]);
        }
        __syncthreads();
    }

#pragma unroll
    for (int i = 0; i < 4; ++i) {
        const int row = rowBase + ty * 4 + i;
        float o[4];
#pragma unroll
        for (int j = 0; j < 4; ++j) {
            float v = acc[i][j];
            if (bias) v += bias[colBase + tx * 4 + j];
            if (doRelu) v = fmaxf(v, 0.0f);
            o[j] = v;
        }
        *reinterpret_cast<float4*>(Cz + (size_t)row * ldc + colBase + tx * 4) =
            make_float4(o[0], o[1], o[2], o[3]);
    }
}

// ---------------- attention: one wave per (b, h, query row) ----------------
// qkv layout: [ROWS][3072]: cols [0,1024)=Q, [1024,2048)=K, [2048,3072)=V,
// each as h*64+d. Scores staged in LDS; softmax wave-reduced; PV over d-lanes.
__global__ __launch_bounds__(64)
void attn_kernel(const float* __restrict__ qkv, float* __restrict__ o)
{
    const int idx = blockIdx.x;                 // b*NH*SEQ + h*SEQ + s
    const int s = idx & (SEQ - 1);
    const int h = (idx >> 10) & (NH - 1);
    const int b = idx >> 14;
    const int lane = threadIdx.x;
    __shared__ float q_s[DHEAD];
    __shared__ float p_s[SEQ];
    const float scale = 0.125f;                 // 1/sqrt(64)

    const size_t rowstride = QKVC;
    const float* qrow = qkv + (size_t)(b * SEQ + s) * rowstride + h * 64;
    q_s[lane] = qrow[lane];
    __syncthreads();

    // pass 1: scores for t = lane, lane+64, ... <= s
    float lmax = -INFINITY;
    for (int t = lane; t <= s; t += 64) {
        const float4* kp = reinterpret_cast<const float4*>(
            qkv + (size_t)(b * SEQ + t) * rowstride + DMODEL + h * 64);
        float dot = 0.0f;
#pragma unroll
        for (int u = 0; u < 16; ++u) {
            const float4 kv = kp[u];
            dot += q_s[4*u+0]*kv.x + q_s[4*u+1]*kv.y + q_s[4*u+2]*kv.z + q_s[4*u+3]*kv.w;
        }
        const float sc = dot * scale;
        p_s[t] = sc;
        lmax = fmaxf(lmax, sc);
    }
#pragma unroll
    for (int off = 32; off; off >>= 1) lmax = fmaxf(lmax, __shfl_xor(lmax, off));

    __syncthreads();
    float lsum = 0.0f;
    for (int t = lane; t <= s; t += 64) {
        const float p = __expf(p_s[t] - lmax);
        p_s[t] = p;
        lsum += p;
    }
#pragma unroll
    for (int off = 32; off; off >>= 1) lsum += __shfl_xor(lsum, off);
    const float inv = 1.0f / lsum;
    __syncthreads();

    // pass 3: o[d] = sum_t p[t] * V[t][d], lane = d (coalesced V reads)
    float acc = 0.0f;
    const float* vbase = qkv + (size_t)b * SEQ * rowstride + 2 * DMODEL + h * 64 + lane;
    int t = 0;
    for (; t + 3 <= s; t += 4) {
        acc += p_s[t + 0] * vbase[(size_t)(t + 0) * rowstride];
        acc += p_s[t + 1] * vbase[(size_t)(t + 1) * rowstride];
        acc += p_s[t + 2] * vbase[(size_t)(t + 2) * rowstride];
        acc += p_s[t + 3] * vbase[(size_t)(t + 3) * rowstride];
    }
    for (; t <= s; ++t) acc += p_s[t] * vbase[(size_t)t * rowstride];
    o[(size_t)(b * SEQ + s) * DMODEL + h * 64 + lane] = acc * inv;
}

// ---------------- residual add + LayerNorm (ddof=1, /(std+eps)) ----------------
__global__ __launch_bounds__(256)
void ln_kernel(const float* __restrict__ a, const float* __restrict__ resid,
               const float* __restrict__ g, const float* __restrict__ bb,
               float* __restrict__ out)
{
    const int row = blockIdx.x;
    const int tid = threadIdx.x;
    const size_t base = (size_t)row * DMODEL;
    const float4 av = *reinterpret_cast<const float4*>(a + base + tid * 4);
    const float4 rv = *reinterpret_cast<const float4*>(resid + base + tid * 4);
    const float v0 = av.x + rv.x, v1 = av.y + rv.y, v2 = av.z + rv.z, v3 = av.w + rv.w;

    __shared__ float red[4];
    float sum = v0 + v1 + v2 + v3;
#pragma unroll
    for (int off = 32; off; off >>= 1) sum += __shfl_xor(sum, off);
    if ((tid & 63) == 0) red[tid >> 6] = sum;
    __syncthreads();
    sum = red[0] + red[1] + red[2] + red[3];
    const float mean = sum * (1.0f / DMODEL);

    const float d0 = v0 - mean, d1 = v1 - mean, d2 = v2 - mean, d3 = v3 - mean;
    float sq = d0 * d0 + d1 * d1 + d2 * d2 + d3 * d3;
#pragma unroll
    for (int off = 32; off; off >>= 1) sq += __shfl_xor(sq, off);
    __syncthreads();                       // red reuse
    if ((tid & 63) == 0) red[tid >> 6] = sq;
    __syncthreads();
    sq = red[0] + red[1] + red[2] + red[3];

    const float sd = sqrtf(sq * (1.0f / (DMODEL - 1)));   // unbiased (ddof=1)
    const float inv = 1.0f / (sd + 1e-6f);
    const float4 gv = *reinterpret_cast<const float4*>(g + tid * 4);
    const float4 bv = *reinterpret_cast<const float4*>(bb + tid * 4);
    float4 o;
    o.x = gv.x * d0 * inv + bv.x;
    o.y = gv.y * d1 * inv + bv.y;
    o.z = gv.z * d2 * inv + bv.z;
    o.w = gv.w * d3 * inv + bv.w;
    *reinterpret_cast<float4*>(out + base + tid * 4) = o;
}

extern "C" void kernel_launch(void* const* d_in, const int* in_sizes, int n_in,
                              void* d_out, int out_size, void* d_ws, size_t ws_size,
                              hipStream_t stream)
{
    const int*   tokens = (const int*)  d_in[0];
    const float* emb    = (const float*)d_in[1];
    const float* Wq     = (const float*)d_in[2];
    const float* Wk     = (const float*)d_in[3];
    const float* Wv     = (const float*)d_in[4];
    const float* Wo     = (const float*)d_in[5];
    const float* bo     = (const float*)d_in[6];
    const float* ln1g   = (const float*)d_in[7];
    const float* ln1b   = (const float*)d_in[8];
    const float* W1     = (const float*)d_in[9];
    const float* b1     = (const float*)d_in[10];
    const float* W2     = (const float*)d_in[11];
    const float* b2     = (const float*)d_in[12];
    const float* ln2g   = (const float*)d_in[13];
    const float* ln2b   = (const float*)d_in[14];
    const float* Wout   = (const float*)d_in[15];
    const float* bout   = (const float*)d_in[16];
    float* out = (float*)d_out;

    // workspace layout (floats); total ~23.1M floats = ~88 MB
    float* ws    = (float*)d_ws;
    float* qkv   = ws;                                  // ROWS*3072
    float* attno = qkv   + (size_t)ROWS * QKVC;         // ROWS*1024
    float* fbuf  = attno + (size_t)ROWS * DMODEL;       // ROWS*1024
    float* hbuf  = fbuf  + (size_t)ROWS * DMODEL;       // ROWS*4096
    float* xA    = hbuf  + (size_t)ROWS * DFFN;         // ROWS*1024
    float* xB    = xA    + (size_t)ROWS * DMODEL;       // ROWS*1024

    const dim3 tb(16, 16);
    embed_kernel<<<ROWS, 256, 0, stream>>>(tokens, emb, xA);

    for (int l = 0; l < LAYERS; ++l) {
        const size_t wqkvOff = (size_t)l * NH * DMODEL * DHEAD;
        const float* Wql = Wq + wqkvOff;
        const float* Wkl = Wk + wqkvOff;
        const float* Wvl = Wv + wqkvOff;
        const float* Wol = Wo + (size_t)l * DMODEL * DMODEL;

        // QKV projections: per-head batched via grid.z (B is [H][DM][64] h-major)
        gemm64_kernel<<<dim3(1, ROWS / 64, NH), tb, 0, stream>>>(
            xA, DMODEL, Wql, DHEAD, (long long)DMODEL * DHEAD,
            qkv, QKVC, 64, nullptr, DMODEL, 0);
        gemm64_kernel<<<dim3(1, ROWS / 64, NH), tb, 0, stream>>>(
            xA, DMODEL, Wkl, DHEAD, (long long)DMODEL * DHEAD,
            qkv + DMODEL, QKVC, 64, nullptr, DMODEL, 0);
        gemm64_kernel<<<dim3(1, ROWS / 64, NH), tb, 0, stream>>>(
            xA, DMODEL, Wvl, DHEAD, (long long)DMODEL * DHEAD,
            qkv + 2 * DMODEL, QKVC, 64, nullptr, DMODEL, 0);

        attn_kernel<<<BATCH * NH * SEQ, 64, 0, stream>>>(qkv, attno);

        // output projection + bias
        gemm64_kernel<<<dim3(DMODEL / 64, ROWS / 64, 1), tb, 0, stream>>>(
            attno, DMODEL, Wol, DMODEL, 0, fbuf, DMODEL, 0,
            bo + (size_t)l * DMODEL, DMODEL, 0);
        // x = LN1(oproj + x)
        ln_kernel<<<ROWS, 256, 0, stream>>>(
            fbuf, xA, ln1g + (size_t)l * DMODEL, ln1b + (size_t)l * DMODEL, xB);

        // FFN
        gemm64_kernel<<<dim3(DFFN / 64, ROWS / 64, 1), tb, 0, stream>>>(
            xB, DMODEL, W1 + (size_t)l * DMODEL * DFFN, DFFN, 0, hbuf, DFFN, 0,
            b1 + (size_t)l * DFFN, DMODEL, 1);
        gemm64_kernel<<<dim3(DMODEL / 64, ROWS / 64, 1), tb, 0, stream>>>(
            hbuf, DFFN, W2 + (size_t)l * DFFN * DMODEL, DMODEL, 0, fbuf, DMODEL, 0,
            b2 + (size_t)l * DMODEL, DFFN, 0);
        // x = LN2(ffn + x)
        ln_kernel<<<ROWS, 256, 0, stream>>>(
            fbuf, xB, ln2g + (size_t)l * DMODEL, ln2b + (size_t)l * DMODEL, xA);
    }

    // final projection to vocab (fp32 out)
    gemm64_kernel<<<dim3(VOCAB / 64, ROWS / 64, 1), tb, 0, stream>>>(
        xA, DMODEL, Wout, VOCAB, 0, out, VOCAB, 0, bout, DMODEL, 0);
}